// Round 15
// baseline (498.687 us; speedup 1.0000x reference)
//
#include <hip/hip_runtime.h>
#include <hip/hip_bf16.h>

// ---------------- problem constants ----------------
#define N_FRAMES 2048          // T*B
#define T_STEPS  128
#define BATCH    16
#define UNITS    128
#define NORM_SCALE 11.313708498984760390f  // sqrt(128)

typedef short bf16x8 __attribute__((ext_vector_type(8)));
typedef float f32x4 __attribute__((ext_vector_type(4)));

static __device__ inline unsigned short f2bf(float f) {
    __hip_bfloat16 h = __float2bfloat16(f);
    return __builtin_bit_cast(unsigned short, h);
}
static __device__ inline float bf2f(unsigned short u) {
    unsigned int x = ((unsigned int)u) << 16;
    return __builtin_bit_cast(float, x);
}

// ---------------- workspace layout (float elements) ----------------
static const size_t OFF_W1P   = 0;            // 16KB ush: conv1 MFMA weights [ky][nt][lane][8]
static const size_t OFF_W2P   = 6144;         // 64KB ush: conv2 MFMA B-frags [16][4][64][8]
static const size_t OFF_W3P   = 38912;        // 72KB ush: conv3 MFMA B-frags [9][2][4][64][8]
static const size_t OFF_FCWP  = 75776;        // ush: fc MFMA B-frags [100][32][64][8] (819200 floats)
static const size_t OFF_WSC   = 894976;       // 64KB ush: scan W^T A-frags [2][8][4][64][8] (16384 floats)
static const size_t OFF_HSR   = 1681408;      // 524288 f32: hs packed float2 [2048][128]{r,i}
static const size_t OFF_PROJR = 2205696;      // 262144 u32: proj packed bf16x2 [2048][128]
static const size_t OFF_H     = 2729984;      // 1048576 : fc output [2048][512] f32
static const size_t OFF_Y2    = 3778560;      // ush: y2 bf16 [2048][9][9][64]
static const size_t OFF_Y1    = 14395392;     // ush: y1 bf16 [2048][20][20][32]
static const size_t OFF_Y3    = OFF_Y1;       // ush: y3 bf16 [2048][3136]

// ---------------- weight permutes ----------------
__global__ void permute_w1mf(const float* __restrict__ w, unsigned short* __restrict__ o) {
    int i = blockIdx.x * 256 + threadIdx.x;      // 8192
    if (i >= 8192) return;
    int j = i & 7; int lane = (i >> 3) & 63; int nt = (i >> 9) & 1; int ky = i >> 10;
    int t = (lane >> 4) * 8 + j;
    int oc = nt * 16 + (lane & 15);
    float v = 0.f;
    if (t < 24) {
        int kx = t / 3, ic = t % 3;
        v = w[((oc * 3 + ic) * 8 + ky) * 8 + kx] * (1.0f / 255.0f);
    }
    o[i] = f2bf(v);
}
__global__ void permute_w2mf(const float* __restrict__ w, unsigned short* __restrict__ o) {
    int i = blockIdx.x * 256 + threadIdx.x;      // 32768
    if (i >= 32768) return;
    int j = i & 7; int lane = (i >> 3) & 63; int nt = (i >> 9) & 3; int kk = i >> 11;
    int ic = (lane >> 4) * 8 + j;
    int oc = nt * 16 + (lane & 15);
    int ky = kk >> 2, kx = kk & 3;
    o[i] = f2bf(w[((oc * 32 + ic) * 4 + ky) * 4 + kx]);
}
__global__ void permute_w3mf(const float* __restrict__ w, unsigned short* __restrict__ o) {
    int i = blockIdx.x * 256 + threadIdx.x;      // 36864
    if (i >= 36864) return;
    int j = i & 7; int lane = (i >> 3) & 63; int nt = (i >> 9) & 3; int c = (i >> 11) & 1; int kk = i >> 12;
    int ic = c * 32 + (lane >> 4) * 8 + j;
    int oc = nt * 16 + (lane & 15);
    int ky = kk / 3, kx = kk % 3;
    o[i] = f2bf(w[((oc * 64 + ic) * 3 + ky) * 3 + kx]);
}
__global__ void permute_fcwmf(const float* __restrict__ w, unsigned short* __restrict__ o) {
    int i = blockIdx.x * 256 + threadIdx.x;      // 1638400
    if (i >= 1638400) return;
    int jj = i & 7; int lane = (i >> 3) & 63; int ntg = (i >> 9) & 31; int kk = i >> 14;
    int k = kk * 32 + (lane >> 4) * 8 + jj;
    int n = ntg * 16 + (lane & 15);
    float v = 0.f;
    if (k < 3136) {
        int p = k >> 6, c = k & 63;
        v = w[(size_t)(c * 49 + p) * 512 + n];
    }
    o[i] = f2bf(v);
}
// scan W^T A-frags: o[((comp*8+mt)*4+ks)*512 + lane*8 + j] = wrec_c[k][u],
// k = ks*32 + (lane>>4)*8 + j, u = mt*16 + (lane&15)
__global__ void permute_wscan(const float* __restrict__ wr, const float* __restrict__ wi,
                              unsigned short* __restrict__ o) {
    int i = blockIdx.x * 256 + threadIdx.x;      // 32768
    if (i >= 32768) return;
    int j = i & 7; int lane = (i >> 3) & 63; int ks = (i >> 9) & 3; int mt = (i >> 11) & 7;
    int comp = i >> 14;
    int k = ks * 32 + (lane >> 4) * 8 + j;
    int u = mt * 16 + (lane & 15);
    const float* src = comp ? wi : wr;
    o[i] = f2bf(src[k * 128 + u]);
}

// ---------------- conv1 v6 (unchanged) ----------------
__global__ __launch_bounds__(256) void conv1_kernel(const float* __restrict__ x,
                                                    const unsigned short* __restrict__ wmf,
                                                    const float* __restrict__ b,
                                                    unsigned short* __restrict__ y) {
    __shared__ unsigned short xs[11096];
    int tid = threadIdx.x;
    int blk = blockIdx.x;
    int n = blk >> 1, hb = blk & 1;

    const float4* xb4 = reinterpret_cast<const float4*>(x + (size_t)n * 21168 + hb * 40 * 252);
#pragma unroll
    for (int it = 0; it < 11; ++it) {
        int i = it * 256 + tid;
        if (i < 2772) {
            float4 v = xb4[i];
            ushort4 h;
            h.x = f2bf(v.x); h.y = f2bf(v.y); h.z = f2bf(v.z); h.w = f2bf(v.w);
            *reinterpret_cast<ushort4*>(&xs[i * 4]) = h;
        }
    }
    if (tid < 8) xs[11088 + tid] = 0;
    __syncthreads();

    int lane = tid & 63;
    int wv = tid >> 6;
    int row = lane & 15;
    int seg = lane >> 4;
    const uint4* wm = reinterpret_cast<const uint4*>(wmf);
    float b0 = b[row];
    float b1 = b[16 + row];
    int pbase = n * 400 + hb * 200;

    for (int tile = wv; tile < 13; tile += 4) {
        int p = tile * 16 + row; if (p > 199) p = 199;
        int eb = (p / 20) * 1008 + (p % 20) * 12 + seg * 8;
        f32x4 acc0 = {0.f, 0.f, 0.f, 0.f};
        f32x4 acc1 = {0.f, 0.f, 0.f, 0.f};
#pragma unroll
        for (int ky = 0; ky < 8; ++ky) {
            int ea = eb + ky * 252;
            ushort4 lo = *reinterpret_cast<const ushort4*>(&xs[ea]);
            ushort4 hi = *reinterpret_cast<const ushort4*>(&xs[ea + 4]);
            bf16x8 a = {(short)lo.x, (short)lo.y, (short)lo.z, (short)lo.w,
                        (short)hi.x, (short)hi.y, (short)hi.z, (short)hi.w};
            bf16x8 w0 = __builtin_bit_cast(bf16x8, wm[(ky * 2 + 0) * 64 + lane]);
            bf16x8 w1 = __builtin_bit_cast(bf16x8, wm[(ky * 2 + 1) * 64 + lane]);
            acc0 = __builtin_amdgcn_mfma_f32_16x16x32_bf16(a, w0, acc0, 0, 0, 0);
            acc1 = __builtin_amdgcn_mfma_f32_16x16x32_bf16(a, w1, acc1, 0, 0, 0);
        }
#pragma unroll
        for (int r = 0; r < 4; ++r) {
            int pl = tile * 16 + seg * 4 + r;
            if (pl < 200) {
                unsigned short* yp = y + ((size_t)(pbase + pl)) * 32 + row;
                yp[0]  = f2bf(fmaxf(acc0[r] + b0, 0.f));
                yp[16] = f2bf(fmaxf(acc1[r] + b1, 0.f));
            }
        }
    }
}

// ---------------- conv2 v5 (unchanged) ----------------
__global__ __launch_bounds__(256) void conv2_kernel(const unsigned short* __restrict__ y1b,
                                                    const unsigned short* __restrict__ wt,
                                                    const float* __restrict__ b,
                                                    unsigned short* __restrict__ y2) {
    __shared__ unsigned short xs[2 * 12800];
    int tid = threadIdx.x;
    int n0 = blockIdx.x * 2;
    const uint4* xg = reinterpret_cast<const uint4*>(y1b + (size_t)n0 * 12800);
    uint4* xs4 = reinterpret_cast<uint4*>(xs);
#pragma unroll
    for (int q = 0; q < 13; ++q) {
        int i = q * 256 + tid;
        if (i < 3200) {
            uint4 v = xg[i];
            int swz = (i & ~3) | ((i & 3) ^ ((i >> 3) & 3));
            xs4[swz] = v;
        }
    }
    __syncthreads();

    int lane = tid & 63;
    int wv = tid >> 6;
    int img = wv >> 1;
    int tbase = (wv & 1) * 3;
    int row = lane & 15, seg = lane >> 4;
    int imgb = img * 1600;

    int ibase[3];
#pragma unroll
    for (int t = 0; t < 3; ++t) {
        int p = (tbase + t) * 16 + row; if (p > 80) p = 80;
        ibase[t] = (p / 9) * 40 + (p % 9) * 2;
    }
    const uint4* B4 = reinterpret_cast<const uint4*>(wt);
    f32x4 acc[3][4];
#pragma unroll
    for (int t = 0; t < 3; ++t)
#pragma unroll
        for (int nt = 0; nt < 4; ++nt) acc[t][nt] = (f32x4){0.f, 0.f, 0.f, 0.f};

#pragma unroll 1
    for (int kk = 0; kk < 16; ++kk) {
        int ky = kk >> 2, kx = kk & 3;
        int koff = ky * 20 + kx;
        bf16x8 bb[4];
#pragma unroll
        for (int nt = 0; nt < 4; ++nt)
            bb[nt] = __builtin_bit_cast(bf16x8, B4[(kk * 4 + nt) * 64 + lane]);
        bf16x8 a[3];
#pragma unroll
        for (int t = 0; t < 3; ++t) {
            int ipx = ibase[t] + koff;
            int a16 = imgb + ipx * 4 + (seg ^ ((ipx >> 1) & 3));
            a[t] = __builtin_bit_cast(bf16x8, *reinterpret_cast<const uint4*>(&xs[a16 * 8]));
        }
#pragma unroll
        for (int t = 0; t < 3; ++t)
#pragma unroll
            for (int nt = 0; nt < 4; ++nt)
                acc[t][nt] = __builtin_amdgcn_mfma_f32_16x16x32_bf16(a[t], bb[nt], acc[t][nt], 0, 0, 0);
    }

#pragma unroll
    for (int nt = 0; nt < 4; ++nt) {
        int c = nt * 16 + row;
        float bc = b[c];
#pragma unroll
        for (int t = 0; t < 3; ++t)
#pragma unroll
            for (int r = 0; r < 4; ++r) {
                int p = (tbase + t) * 16 + seg * 4 + r;
                if (p < 81)
                    y2[((size_t)(n0 + img) * 81 + p) * 64 + c] = f2bf(fmaxf(acc[t][nt][r] + bc, 0.f));
            }
    }
}

// ---------------- conv3 v5 (unchanged) ----------------
__global__ __launch_bounds__(256) void conv3_kernel(const unsigned short* __restrict__ y2b,
                                                    const unsigned short* __restrict__ wt,
                                                    const float* __restrict__ b,
                                                    unsigned short* __restrict__ y3) {
    __shared__ unsigned short xs[2 * 5184];
    int tid = threadIdx.x;
    int n0 = blockIdx.x * 2;
    const uint4* xg = reinterpret_cast<const uint4*>(y2b + (size_t)n0 * 5184);
    uint4* xs4 = reinterpret_cast<uint4*>(xs);
#pragma unroll
    for (int q = 0; q < 6; ++q) {
        int i = q * 256 + tid;
        if (i < 1296) {
            uint4 v = xg[i];
            int px = i >> 3, qq = i & 7;
            xs4[px * 8 + (qq ^ (px & 7))] = v;
        }
    }
    __syncthreads();

    int lane = tid & 63;
    int wv = tid >> 6;
    int img = wv >> 1;
    int tbase = (wv & 1) * 2;
    int row = lane & 15, seg = lane >> 4;

    int ibase[2];
#pragma unroll
    for (int t = 0; t < 2; ++t) {
        int p = (tbase + t) * 16 + row; if (p > 48) p = 48;
        ibase[t] = img * 81 + (p / 7) * 9 + (p % 7);
    }
    const uint4* B4 = reinterpret_cast<const uint4*>(wt);
    f32x4 acc[2][4];
#pragma unroll
    for (int t = 0; t < 2; ++t)
#pragma unroll
        for (int nt = 0; nt < 4; ++nt) acc[t][nt] = (f32x4){0.f, 0.f, 0.f, 0.f};

#pragma unroll 1
    for (int kk = 0; kk < 9; ++kk) {
        int ky = kk / 3, kx = kk % 3;
        int koff = ky * 9 + kx;
#pragma unroll
        for (int c = 0; c < 2; ++c) {
            bf16x8 bb[4];
#pragma unroll
            for (int nt = 0; nt < 4; ++nt)
                bb[nt] = __builtin_bit_cast(bf16x8, B4[((kk * 2 + c) * 4 + nt) * 64 + lane]);
            bf16x8 a[2];
#pragma unroll
            for (int t = 0; t < 2; ++t) {
                int px = ibase[t] + koff;
                int u16 = px * 8 + ((c * 4 + seg) ^ (px & 7));
                a[t] = __builtin_bit_cast(bf16x8, *reinterpret_cast<const uint4*>(&xs[u16 * 8]));
            }
#pragma unroll
            for (int t = 0; t < 2; ++t)
#pragma unroll
                for (int nt = 0; nt < 4; ++nt)
                    acc[t][nt] = __builtin_amdgcn_mfma_f32_16x16x32_bf16(a[t], bb[nt], acc[t][nt], 0, 0, 0);
        }
    }

#pragma unroll
    for (int nt = 0; nt < 4; ++nt) {
        int c = nt * 16 + row;
        float bc = b[c];
#pragma unroll
        for (int t = 0; t < 2; ++t)
#pragma unroll
            for (int r = 0; r < 4; ++r) {
                int p = (tbase + t) * 16 + seg * 4 + r;
                if (p < 49)
                    y3[(size_t)(n0 + img) * 3136 + p * 64 + c] = f2bf(fmaxf(acc[t][nt][r] + bc, 0.f));
            }
    }
}

// ---------------- FC v2 (unchanged) ----------------
__global__ __launch_bounds__(256) void fc_kernel(const unsigned short* __restrict__ A,
                                                 const unsigned short* __restrict__ Bt,
                                                 const float* __restrict__ bias,
                                                 float* __restrict__ C) {
    __shared__ float Cs[64][65];
    int tid = threadIdx.x;
    int lane = tid & 63;
    int wv = tid >> 6;
    int bm = blockIdx.x & 31;
    int bn = blockIdx.x >> 5;
    int row = lane & 15, seg = lane >> 4;

    const uint4* B4 = reinterpret_cast<const uint4*>(Bt);
    f32x4 acc[4][4];
#pragma unroll
    for (int mf = 0; mf < 4; ++mf)
#pragma unroll
        for (int nf = 0; nf < 4; ++nf) acc[mf][nf] = (f32x4){0.f, 0.f, 0.f, 0.f};

    const unsigned short* Abase = A + (size_t)(bm * 64 + row) * 3136 + seg * 8;

#pragma unroll 1
    for (int kk = wv; kk < 100; kk += 4) {
        bf16x8 a[4], bb[4];
#pragma unroll
        for (int mf = 0; mf < 4; ++mf)
            a[mf] = __builtin_bit_cast(bf16x8,
                *reinterpret_cast<const uint4*>(Abase + (size_t)mf * 16 * 3136 + kk * 32));
#pragma unroll
        for (int nf = 0; nf < 4; ++nf)
            bb[nf] = __builtin_bit_cast(bf16x8, B4[(kk * 32 + bn * 4 + nf) * 64 + lane]);
#pragma unroll
        for (int mf = 0; mf < 4; ++mf)
#pragma unroll
            for (int nf = 0; nf < 4; ++nf)
                acc[mf][nf] = __builtin_amdgcn_mfma_f32_16x16x32_bf16(a[mf], bb[nf], acc[mf][nf], 0, 0, 0);
    }

#pragma unroll 1
    for (int w = 0; w < 4; ++w) {
        if (wv == w) {
#pragma unroll
            for (int mf = 0; mf < 4; ++mf)
#pragma unroll
                for (int nf = 0; nf < 4; ++nf)
#pragma unroll
                    for (int r = 0; r < 4; ++r) {
                        int rr = mf * 16 + seg * 4 + r;
                        int cc = nf * 16 + row;
                        if (w == 0) Cs[rr][cc] = acc[mf][nf][r];
                        else        Cs[rr][cc] += acc[mf][nf][r];
                    }
        }
        __syncthreads();
    }

    int r = tid >> 2, cq = (tid & 3) * 16;
#pragma unroll
    for (int q = 0; q < 4; ++q) {
        int c0 = cq + q * 4;
        float4 v = *reinterpret_cast<float4*>(&Cs[r][c0]);
        float4 bv = *reinterpret_cast<const float4*>(&bias[bn * 64 + c0]);
        v.x = fmaxf(v.x + bv.x, 0.f);
        v.y = fmaxf(v.y + bv.y, 0.f);
        v.z = fmaxf(v.z + bv.z, 0.f);
        v.w = fmaxf(v.w + bv.w, 0.f);
        *reinterpret_cast<float4*>(&C[(size_t)(bm * 64 + r) * 512 + bn * 64 + c0]) = v;
    }
}

// ---------------- proj: packed bf16x2 (u32) output ----------------
__global__ __launch_bounds__(256) void proj_kernel(const float* __restrict__ h,
                                                   const float* __restrict__ winr,
                                                   const float* __restrict__ wini,
                                                   unsigned int* __restrict__ pj) {
    int idx = blockIdx.x * 256 + threadIdx.x;
    int u = idx & 127;
    int n0 = (idx >> 7) * 8;
    float ar[8] = {}, ai[8] = {};
    for (int k = 0; k < 512; ++k) {
        float wrv = winr[k * 128 + u], wiv = wini[k * 128 + u];
#pragma unroll
        for (int g = 0; g < 8; ++g) {
            float hv = h[(size_t)(n0 + g) * 512 + k];
            ar[g] = fmaf(hv, wrv, ar[g]);
            ai[g] = fmaf(hv, wiv, ai[g]);
        }
    }
#pragma unroll
    for (int g = 0; g < 8; ++g)
        pj[(size_t)(n0 + g) * 128 + u] = (unsigned int)f2bf(ar[g]) | ((unsigned int)f2bf(ai[g]) << 16);
}

// ---------------- RNN scan v6: SINGLE WAVE, no barriers ----------------
// D = W^T_c @ S^T_c : A = W^T frags (8 mt, 4 ks, 2 comp = 256 VGPR, pinned),
// B = state^T (col = batch). D: lane holds b = lane&15, u = mt*16 + seg*4 + r.
// Norm: intra-wave shfl_xor(16,32). Relayout D->B via same-wave LDS (no barrier).
__global__ __launch_bounds__(64, 1) void scan_kernel(const float* __restrict__ done,
                                                     const float* __restrict__ sr0,
                                                     const float* __restrict__ si0,
                                                     const unsigned short* __restrict__ wsc,
                                                     const unsigned int* __restrict__ pj,
                                                     float2* __restrict__ hs) {
    __shared__ __align__(16) unsigned int stR[1024], stI[1024];   // [b][upair] swizzled
    __shared__ float done_l[2048];
    int lane = threadIdx.x;
    int b = lane & 15, seg = lane >> 4;
    int swz = (b & 3) << 3;

    // weights: W^T A-frags, pinned resident (256 VGPR)
    const uint4* W4 = reinterpret_cast<const uint4*>(wsc);
    bf16x8 WR[8][4], WI[8][4];
#pragma unroll
    for (int mt = 0; mt < 8; ++mt)
#pragma unroll
        for (int ks = 0; ks < 4; ++ks) {
            WR[mt][ks] = __builtin_bit_cast(bf16x8, W4[((0 * 8 + mt) * 4 + ks) * 64 + lane]);
            WI[mt][ks] = __builtin_bit_cast(bf16x8, W4[((1 * 8 + mt) * 4 + ks) * 64 + lane]);
        }
#pragma unroll
    for (int mt = 0; mt < 8; ++mt) {
        asm volatile("" : "+v"(WR[mt][0]), "+v"(WR[mt][1]), "+v"(WR[mt][2]), "+v"(WR[mt][3]));
        asm volatile("" : "+v"(WI[mt][0]), "+v"(WI[mt][1]), "+v"(WI[mt][2]), "+v"(WI[mt][3]));
    }

    // done -> LDS
    for (int e = lane; e < 2048; e += 64) done_l[e] = done[e];

    // state init (done[0] blend), packed bf16 pairs into swizzled LDS
    for (int p = lane; p < 1024; p += 64) {
        int bb = p >> 6, upair = p & 63;
        int u0 = upair * 2;
        float d = done[bb];
        float rr = 1.f - d;
        float sr0v = rr * sr0[bb * 128 + u0] + d;
        float sr1v = rr * sr0[bb * 128 + u0 + 1] + d;
        float si0v = rr * si0[bb * 128 + u0];
        float si1v = rr * si0[bb * 128 + u0 + 1];
        int addr = bb * 64 + (upair ^ ((bb & 3) << 3));
        stR[addr] = (unsigned int)f2bf(sr0v) | ((unsigned int)f2bf(sr1v) << 16);
        stI[addr] = (unsigned int)f2bf(si0v) | ((unsigned int)f2bf(si1v) << 16);
    }

    // prefetch pj t=0 : pjc[mt] = uint4 covering r=0..3 at u = mt*16+seg*4
    uint4 pjc[8];
#pragma unroll
    for (int mt = 0; mt < 8; ++mt)
        pjc[mt] = *reinterpret_cast<const uint4*>(&pj[(size_t)b * 128 + mt * 16 + seg * 4]);

    for (int t = 0; t < T_STEPS; ++t) {
        // ensure prior LDS writes (init or last step) are visible before reads
        asm volatile("s_waitcnt lgkmcnt(0)" ::: "memory");
        __builtin_amdgcn_sched_barrier(0);

        // B-frags: state^T, col=b, k = ks*32 + seg*8 + j
        bf16x8 SBr[4], SBi[4], SBin[4];
#pragma unroll
        for (int ks = 0; ks < 4; ++ks) {
            int addr = b * 64 + ((ks * 16 + seg * 4) ^ swz);
            uint4 vr = *reinterpret_cast<const uint4*>(&stR[addr]);
            uint4 vi = *reinterpret_cast<const uint4*>(&stI[addr]);
            SBr[ks] = __builtin_bit_cast(bf16x8, vr);
            SBi[ks] = __builtin_bit_cast(bf16x8, vi);
            uint4 vn = {vi.x ^ 0x80008000u, vi.y ^ 0x80008000u,
                        vi.z ^ 0x80008000u, vi.w ^ 0x80008000u};
            SBin[ks] = __builtin_bit_cast(bf16x8, vn);
        }

        // MFMA: 8 mt x 4 ks x 4 (complex)
        f32x4 accR[8], accI[8];
#pragma unroll
        for (int mt = 0; mt < 8; ++mt) {
            accR[mt] = (f32x4){0.f, 0.f, 0.f, 0.f};
            accI[mt] = (f32x4){0.f, 0.f, 0.f, 0.f};
        }
#pragma unroll
        for (int ks = 0; ks < 4; ++ks)
#pragma unroll
            for (int mt = 0; mt < 8; ++mt) {
                accR[mt] = __builtin_amdgcn_mfma_f32_16x16x32_bf16(WR[mt][ks], SBr[ks], accR[mt], 0, 0, 0);
                accR[mt] = __builtin_amdgcn_mfma_f32_16x16x32_bf16(WI[mt][ks], SBin[ks], accR[mt], 0, 0, 0);
                accI[mt] = __builtin_amdgcn_mfma_f32_16x16x32_bf16(WR[mt][ks], SBi[ks], accI[mt], 0, 0, 0);
                accI[mt] = __builtin_amdgcn_mfma_f32_16x16x32_bf16(WI[mt][ks], SBr[ks], accI[mt], 0, 0, 0);
            }

        // pre = acc + pj ; local norm partial
        float prer[8][4], prei[8][4];
        float sq = 0.f;
#pragma unroll
        for (int mt = 0; mt < 8; ++mt) {
            unsigned int pw[4] = {pjc[mt].x, pjc[mt].y, pjc[mt].z, pjc[mt].w};
#pragma unroll
            for (int r = 0; r < 4; ++r) {
                float pr_ = bf2f((unsigned short)(pw[r] & 0xffff));
                float pi_ = bf2f((unsigned short)(pw[r] >> 16));
                prer[mt][r] = accR[mt][r] + pr_;
                prei[mt][r] = accI[mt][r] + pi_;
                sq = fmaf(prer[mt][r], prer[mt][r], sq);
                sq = fmaf(prei[mt][r], prei[mt][r], sq);
            }
        }
        // reduce across segs (b preserved)
        sq += __shfl_xor(sq, 16);
        sq += __shfl_xor(sq, 32);
        float scale = NORM_SCALE * rsqrtf(sq);

        // next-step pj prefetch (issued now, consumed next iter after MFMA)
        int tn = (t + 1 < T_STEPS) ? t + 1 : 127;
        uint4 pjn[8];
#pragma unroll
        for (int mt = 0; mt < 8; ++mt)
            pjn[mt] = *reinterpret_cast<const uint4*>(&pj[(size_t)(tn * 16 + b) * 128 + mt * 16 + seg * 4]);

        float dn = (t + 1 < T_STEPS) ? done_l[(t + 1) * 16 + b] : 0.f;
        float rr = 1.f - dn;

        // normalize, store hs, blend, pack, write state LDS
#pragma unroll
        for (int mt = 0; mt < 8; ++mt) {
            float nr[4], ni[4];
#pragma unroll
            for (int r = 0; r < 4; ++r) {
                nr[r] = prer[mt][r] * scale;
                ni[r] = prei[mt][r] * scale;
            }
            // hs store: float2 x4 contiguous (u = mt*16+seg*4 .. +3)
            float4 h0 = {nr[0], ni[0], nr[1], ni[1]};
            float4 h1 = {nr[2], ni[2], nr[3], ni[3]};
            float* hp = reinterpret_cast<float*>(&hs[(size_t)(t * 16 + b) * 128 + mt * 16 + seg * 4]);
            *reinterpret_cast<float4*>(hp) = h0;
            *reinterpret_cast<float4*>(hp + 4) = h1;
            // blend + pack pairs
            unsigned int p0 = (unsigned int)f2bf(fmaf(rr, nr[0], dn)) |
                              ((unsigned int)f2bf(fmaf(rr, nr[1], dn)) << 16);
            unsigned int p1 = (unsigned int)f2bf(fmaf(rr, nr[2], dn)) |
                              ((unsigned int)f2bf(fmaf(rr, nr[3], dn)) << 16);
            unsigned int q0 = (unsigned int)f2bf(rr * ni[0]) | ((unsigned int)f2bf(rr * ni[1]) << 16);
            unsigned int q1 = (unsigned int)f2bf(rr * ni[2]) | ((unsigned int)f2bf(rr * ni[3]) << 16);
            int addr = b * 64 + ((mt * 8 + seg * 2) ^ swz);
            *reinterpret_cast<uint2*>(&stR[addr]) = make_uint2(p0, p1);
            *reinterpret_cast<uint2*>(&stI[addr]) = make_uint2(q0, q1);
        }
#pragma unroll
        for (int mt = 0; mt < 8; ++mt) pjc[mt] = pjn[mt];
    }
}

// ---------------- heads (unchanged) ----------------
__global__ void heads_kernel(const float2* __restrict__ hs,
                             const float* __restrict__ aw, const float* __restrict__ ab,
                             const float* __restrict__ cw, const float* __restrict__ cb,
                             float* __restrict__ out) {
    int idx = blockIdx.x * 256 + threadIdx.x;
    if (idx >= N_FRAMES * 7) return;
    int j = idx % 7;
    int n = idx / 7;
    const float2* hp = hs + (size_t)n * 128;
    float acc;
    if (j < 6) {
        acc = ab[j];
        for (int k = 0; k < 128; ++k) {
            float2 v = hp[k];
            acc = fmaf(v.x, aw[k * 6 + j], acc);
            acc = fmaf(v.y, aw[(128 + k) * 6 + j], acc);
        }
    } else {
        acc = cb[0];
        for (int k = 0; k < 128; ++k) {
            float2 v = hp[k];
            acc = fmaf(v.x, cw[k], acc);
            acc = fmaf(v.y, cw[128 + k], acc);
        }
    }
    out[idx] = acc;
}

// ---------------- launch ----------------
extern "C" void kernel_launch(void* const* d_in, const int* in_sizes, int n_in,
                              void* d_out, int out_size, void* d_ws, size_t ws_size,
                              hipStream_t stream) {
    const float* x        = (const float*)d_in[0];
    const float* done     = (const float*)d_in[1];
    const float* sr0      = (const float*)d_in[2];
    const float* si0      = (const float*)d_in[3];
    const float* conv1_w  = (const float*)d_in[4];
    const float* conv1_b  = (const float*)d_in[5];
    const float* conv2_w  = (const float*)d_in[6];
    const float* conv2_b  = (const float*)d_in[7];
    const float* conv3_w  = (const float*)d_in[8];
    const float* conv3_b  = (const float*)d_in[9];
    const float* fc_w     = (const float*)d_in[10];
    const float* fc_b     = (const float*)d_in[11];
    const float* win_r    = (const float*)d_in[12];
    const float* win_i    = (const float*)d_in[13];
    const float* wrec_r   = (const float*)d_in[14];
    const float* wrec_i   = (const float*)d_in[15];
    const float* actor_w  = (const float*)d_in[16];
    const float* actor_b  = (const float*)d_in[17];
    const float* critic_w = (const float*)d_in[18];
    const float* critic_b = (const float*)d_in[19];

    float* ws = (float*)d_ws;
    unsigned short* w1mf = (unsigned short*)(ws + OFF_W1P);
    unsigned short* w2mf = (unsigned short*)(ws + OFF_W2P);
    unsigned short* w3mf = (unsigned short*)(ws + OFF_W3P);
    unsigned short* fcb = (unsigned short*)(ws + OFF_FCWP);
    unsigned short* wsc = (unsigned short*)(ws + OFF_WSC);
    float2* hs  = (float2*)(ws + OFF_HSR);
    unsigned int* pj = (unsigned int*)(ws + OFF_PROJR);
    float* h    = ws + OFF_H;
    unsigned short* y2b = (unsigned short*)(ws + OFF_Y2);
    unsigned short* y1b = (unsigned short*)(ws + OFF_Y1);
    unsigned short* y3b = (unsigned short*)(ws + OFF_Y3);
    float* outp = (float*)d_out;

    hipLaunchKernelGGL(permute_w1mf, dim3(32), dim3(256), 0, stream, conv1_w, w1mf);
    hipLaunchKernelGGL(permute_w2mf, dim3(128), dim3(256), 0, stream, conv2_w, w2mf);
    hipLaunchKernelGGL(permute_w3mf, dim3(144), dim3(256), 0, stream, conv3_w, w3mf);
    hipLaunchKernelGGL(permute_fcwmf, dim3(6400), dim3(256), 0, stream, fc_w, fcb);
    hipLaunchKernelGGL(permute_wscan, dim3(128), dim3(256), 0, stream, wrec_r, wrec_i, wsc);

    hipLaunchKernelGGL(conv1_kernel, dim3(4096), dim3(256), 0, stream, x, w1mf, conv1_b, y1b);
    hipLaunchKernelGGL(conv2_kernel, dim3(1024), dim3(256), 0, stream, y1b, w2mf, conv2_b, y2b);
    hipLaunchKernelGGL(conv3_kernel, dim3(1024), dim3(256), 0, stream, y2b, w3mf, conv3_b, y3b);
    hipLaunchKernelGGL(fc_kernel, dim3(256), dim3(256), 0, stream, y3b, fcb, fc_b, h);
    hipLaunchKernelGGL(proj_kernel, dim3(128), dim3(256), 0, stream, h, win_r, win_i, pj);
    hipLaunchKernelGGL(scan_kernel, dim3(1), dim3(64), 0, stream,
                       done, sr0, si0, wsc, pj, hs);
    hipLaunchKernelGGL(heads_kernel, dim3(56), dim3(256), 0, stream,
                       hs, actor_w, actor_b, critic_w, critic_b, outp);
}

// Round 16
// 401.669 us; speedup vs baseline: 1.2415x; 1.2415x over previous
//
#include <hip/hip_runtime.h>
#include <hip/hip_bf16.h>

// ---------------- problem constants ----------------
#define N_FRAMES 2048          // T*B
#define T_STEPS  128
#define BATCH    16
#define UNITS    128
#define NORM_SCALE 11.313708498984760390f  // sqrt(128)

typedef short bf16x8 __attribute__((ext_vector_type(8)));
typedef float f32x4 __attribute__((ext_vector_type(4)));

static __device__ inline unsigned short f2bf(float f) {
    __hip_bfloat16 h = __float2bfloat16(f);
    return __builtin_bit_cast(unsigned short, h);
}

// LDS-only barrier: drains lgkm (LDS) but leaves global loads/stores in flight.
#define LDS_BARRIER() do { asm volatile("s_waitcnt lgkmcnt(0)" ::: "memory"); \
                           __builtin_amdgcn_s_barrier(); } while (0)

// ---------------- workspace layout (float elements) ----------------
static const size_t OFF_W1P   = 0;            // 16KB ush: conv1 MFMA weights [ky][nt][lane][8]
static const size_t OFF_W2P   = 6144;         // 64KB ush: conv2 MFMA B-frags [16][4][64][8]
static const size_t OFF_W3P   = 38912;        // 72KB ush: conv3 MFMA B-frags [9][2][4][64][8]
static const size_t OFF_FCWP  = 75776;        // ush: fc MFMA B-frags [100][32][64][8] (819200 floats)
static const size_t OFF_WSC   = 894976;       // 64KB ush: scan MFMA B-frags [2][8][4][64][8] (16384 floats)
static const size_t OFF_HSR   = 1681408;      // 524288 f32: hs packed float2 [2048][128]{r,i}
static const size_t OFF_PROJR = 2205696;      // 524288 f32: proj packed float2 [2048][128]{r,i}
static const size_t OFF_H     = 2729984;      // 1048576 : fc output [2048][512] f32
static const size_t OFF_Y2    = 3778560;      // ush: y2 bf16 [2048][9][9][64]
static const size_t OFF_Y1    = 14395392;     // ush: y1 bf16 [2048][20][20][32]
static const size_t OFF_Y3    = OFF_Y1;       // ush: y3 bf16 [2048][3136]

// ---------------- weight permutes ----------------
__global__ void permute_w1mf(const float* __restrict__ w, unsigned short* __restrict__ o) {
    int i = blockIdx.x * 256 + threadIdx.x;      // 8192
    if (i >= 8192) return;
    int j = i & 7; int lane = (i >> 3) & 63; int nt = (i >> 9) & 1; int ky = i >> 10;
    int t = (lane >> 4) * 8 + j;
    int oc = nt * 16 + (lane & 15);
    float v = 0.f;
    if (t < 24) {
        int kx = t / 3, ic = t % 3;
        v = w[((oc * 3 + ic) * 8 + ky) * 8 + kx] * (1.0f / 255.0f);
    }
    o[i] = f2bf(v);
}
__global__ void permute_w2mf(const float* __restrict__ w, unsigned short* __restrict__ o) {
    int i = blockIdx.x * 256 + threadIdx.x;      // 32768
    if (i >= 32768) return;
    int j = i & 7; int lane = (i >> 3) & 63; int nt = (i >> 9) & 3; int kk = i >> 11;
    int ic = (lane >> 4) * 8 + j;
    int oc = nt * 16 + (lane & 15);
    int ky = kk >> 2, kx = kk & 3;
    o[i] = f2bf(w[((oc * 32 + ic) * 4 + ky) * 4 + kx]);
}
__global__ void permute_w3mf(const float* __restrict__ w, unsigned short* __restrict__ o) {
    int i = blockIdx.x * 256 + threadIdx.x;      // 36864
    if (i >= 36864) return;
    int j = i & 7; int lane = (i >> 3) & 63; int nt = (i >> 9) & 3; int c = (i >> 11) & 1; int kk = i >> 12;
    int ic = c * 32 + (lane >> 4) * 8 + j;
    int oc = nt * 16 + (lane & 15);
    int ky = kk / 3, kx = kk % 3;
    o[i] = f2bf(w[((oc * 64 + ic) * 3 + ky) * 3 + kx]);
}
__global__ void permute_fcwmf(const float* __restrict__ w, unsigned short* __restrict__ o) {
    int i = blockIdx.x * 256 + threadIdx.x;      // 1638400
    if (i >= 1638400) return;
    int jj = i & 7; int lane = (i >> 3) & 63; int ntg = (i >> 9) & 31; int kk = i >> 14;
    int k = kk * 32 + (lane >> 4) * 8 + jj;
    int n = ntg * 16 + (lane & 15);
    float v = 0.f;
    if (k < 3136) {
        int p = k >> 6, c = k & 63;
        v = w[(size_t)(c * 49 + p) * 512 + n];
    }
    o[i] = f2bf(v);
}
// scan MFMA B-frags: o[((comp*8+nt)*4+ks)*512 + lane*8 + j] = wrec_{r,i}[k=ks*32+(lane>>4)*8+j][n=nt*16+(lane&15)]
__global__ void permute_wscan(const float* __restrict__ wr, const float* __restrict__ wi,
                              unsigned short* __restrict__ o) {
    int i = blockIdx.x * 256 + threadIdx.x;      // 32768
    if (i >= 32768) return;
    int j = i & 7; int lane = (i >> 3) & 63; int ks = (i >> 9) & 3; int nt = (i >> 11) & 7;
    int comp = i >> 14;
    int k = ks * 32 + (lane >> 4) * 8 + j;
    int n = nt * 16 + (lane & 15);
    const float* src = comp ? wi : wr;
    o[i] = f2bf(src[k * 128 + n]);
}

// ---------------- conv1 v6: MFMA implicit GEMM, bf16 output (unchanged) ----------------
__global__ __launch_bounds__(256) void conv1_kernel(const float* __restrict__ x,
                                                    const unsigned short* __restrict__ wmf,
                                                    const float* __restrict__ b,
                                                    unsigned short* __restrict__ y) {
    __shared__ unsigned short xs[11096];
    int tid = threadIdx.x;
    int blk = blockIdx.x;
    int n = blk >> 1, hb = blk & 1;

    const float4* xb4 = reinterpret_cast<const float4*>(x + (size_t)n * 21168 + hb * 40 * 252);
#pragma unroll
    for (int it = 0; it < 11; ++it) {
        int i = it * 256 + tid;
        if (i < 2772) {
            float4 v = xb4[i];
            ushort4 h;
            h.x = f2bf(v.x); h.y = f2bf(v.y); h.z = f2bf(v.z); h.w = f2bf(v.w);
            *reinterpret_cast<ushort4*>(&xs[i * 4]) = h;
        }
    }
    if (tid < 8) xs[11088 + tid] = 0;
    __syncthreads();

    int lane = tid & 63;
    int wv = tid >> 6;
    int row = lane & 15;
    int seg = lane >> 4;
    const uint4* wm = reinterpret_cast<const uint4*>(wmf);
    float b0 = b[row];
    float b1 = b[16 + row];
    int pbase = n * 400 + hb * 200;

    for (int tile = wv; tile < 13; tile += 4) {
        int p = tile * 16 + row; if (p > 199) p = 199;
        int eb = (p / 20) * 1008 + (p % 20) * 12 + seg * 8;
        f32x4 acc0 = {0.f, 0.f, 0.f, 0.f};
        f32x4 acc1 = {0.f, 0.f, 0.f, 0.f};
#pragma unroll
        for (int ky = 0; ky < 8; ++ky) {
            int ea = eb + ky * 252;
            ushort4 lo = *reinterpret_cast<const ushort4*>(&xs[ea]);
            ushort4 hi = *reinterpret_cast<const ushort4*>(&xs[ea + 4]);
            bf16x8 a = {(short)lo.x, (short)lo.y, (short)lo.z, (short)lo.w,
                        (short)hi.x, (short)hi.y, (short)hi.z, (short)hi.w};
            bf16x8 w0 = __builtin_bit_cast(bf16x8, wm[(ky * 2 + 0) * 64 + lane]);
            bf16x8 w1 = __builtin_bit_cast(bf16x8, wm[(ky * 2 + 1) * 64 + lane]);
            acc0 = __builtin_amdgcn_mfma_f32_16x16x32_bf16(a, w0, acc0, 0, 0, 0);
            acc1 = __builtin_amdgcn_mfma_f32_16x16x32_bf16(a, w1, acc1, 0, 0, 0);
        }
#pragma unroll
        for (int r = 0; r < 4; ++r) {
            int pl = tile * 16 + seg * 4 + r;
            if (pl < 200) {
                unsigned short* yp = y + ((size_t)(pbase + pl)) * 32 + row;
                yp[0]  = f2bf(fmaxf(acc0[r] + b0, 0.f));
                yp[16] = f2bf(fmaxf(acc1[r] + b1, 0.f));
            }
        }
    }
}

// ---------------- conv2 v5: MFMA implicit GEMM, bf16 output (unchanged) ----------------
__global__ __launch_bounds__(256) void conv2_kernel(const unsigned short* __restrict__ y1b,
                                                    const unsigned short* __restrict__ wt,
                                                    const float* __restrict__ b,
                                                    unsigned short* __restrict__ y2) {
    __shared__ unsigned short xs[2 * 12800];
    int tid = threadIdx.x;
    int n0 = blockIdx.x * 2;
    const uint4* xg = reinterpret_cast<const uint4*>(y1b + (size_t)n0 * 12800);
    uint4* xs4 = reinterpret_cast<uint4*>(xs);
#pragma unroll
    for (int q = 0; q < 13; ++q) {
        int i = q * 256 + tid;
        if (i < 3200) {
            uint4 v = xg[i];
            int swz = (i & ~3) | ((i & 3) ^ ((i >> 3) & 3));
            xs4[swz] = v;
        }
    }
    __syncthreads();

    int lane = tid & 63;
    int wv = tid >> 6;
    int img = wv >> 1;
    int tbase = (wv & 1) * 3;
    int row = lane & 15, seg = lane >> 4;
    int imgb = img * 1600;

    int ibase[3];
#pragma unroll
    for (int t = 0; t < 3; ++t) {
        int p = (tbase + t) * 16 + row; if (p > 80) p = 80;
        ibase[t] = (p / 9) * 40 + (p % 9) * 2;
    }
    const uint4* B4 = reinterpret_cast<const uint4*>(wt);
    f32x4 acc[3][4];
#pragma unroll
    for (int t = 0; t < 3; ++t)
#pragma unroll
        for (int nt = 0; nt < 4; ++nt) acc[t][nt] = (f32x4){0.f, 0.f, 0.f, 0.f};

#pragma unroll 1
    for (int kk = 0; kk < 16; ++kk) {
        int ky = kk >> 2, kx = kk & 3;
        int koff = ky * 20 + kx;
        bf16x8 bb[4];
#pragma unroll
        for (int nt = 0; nt < 4; ++nt)
            bb[nt] = __builtin_bit_cast(bf16x8, B4[(kk * 4 + nt) * 64 + lane]);
        bf16x8 a[3];
#pragma unroll
        for (int t = 0; t < 3; ++t) {
            int ipx = ibase[t] + koff;
            int a16 = imgb + ipx * 4 + (seg ^ ((ipx >> 1) & 3));
            a[t] = __builtin_bit_cast(bf16x8, *reinterpret_cast<const uint4*>(&xs[a16 * 8]));
        }
#pragma unroll
        for (int t = 0; t < 3; ++t)
#pragma unroll
            for (int nt = 0; nt < 4; ++nt)
                acc[t][nt] = __builtin_amdgcn_mfma_f32_16x16x32_bf16(a[t], bb[nt], acc[t][nt], 0, 0, 0);
    }

#pragma unroll
    for (int nt = 0; nt < 4; ++nt) {
        int c = nt * 16 + row;
        float bc = b[c];
#pragma unroll
        for (int t = 0; t < 3; ++t)
#pragma unroll
            for (int r = 0; r < 4; ++r) {
                int p = (tbase + t) * 16 + seg * 4 + r;
                if (p < 81)
                    y2[((size_t)(n0 + img) * 81 + p) * 64 + c] = f2bf(fmaxf(acc[t][nt][r] + bc, 0.f));
            }
    }
}

// ---------------- conv3 v5: MFMA implicit GEMM (unchanged) ----------------
__global__ __launch_bounds__(256) void conv3_kernel(const unsigned short* __restrict__ y2b,
                                                    const unsigned short* __restrict__ wt,
                                                    const float* __restrict__ b,
                                                    unsigned short* __restrict__ y3) {
    __shared__ unsigned short xs[2 * 5184];
    int tid = threadIdx.x;
    int n0 = blockIdx.x * 2;
    const uint4* xg = reinterpret_cast<const uint4*>(y2b + (size_t)n0 * 5184);
    uint4* xs4 = reinterpret_cast<uint4*>(xs);
#pragma unroll
    for (int q = 0; q < 6; ++q) {
        int i = q * 256 + tid;
        if (i < 1296) {
            uint4 v = xg[i];
            int px = i >> 3, qq = i & 7;
            xs4[px * 8 + (qq ^ (px & 7))] = v;
        }
    }
    __syncthreads();

    int lane = tid & 63;
    int wv = tid >> 6;
    int img = wv >> 1;
    int tbase = (wv & 1) * 2;
    int row = lane & 15, seg = lane >> 4;

    int ibase[2];
#pragma unroll
    for (int t = 0; t < 2; ++t) {
        int p = (tbase + t) * 16 + row; if (p > 48) p = 48;
        ibase[t] = img * 81 + (p / 7) * 9 + (p % 7);
    }
    const uint4* B4 = reinterpret_cast<const uint4*>(wt);
    f32x4 acc[2][4];
#pragma unroll
    for (int t = 0; t < 2; ++t)
#pragma unroll
        for (int nt = 0; nt < 4; ++nt) acc[t][nt] = (f32x4){0.f, 0.f, 0.f, 0.f};

#pragma unroll 1
    for (int kk = 0; kk < 9; ++kk) {
        int ky = kk / 3, kx = kk % 3;
        int koff = ky * 9 + kx;
#pragma unroll
        for (int c = 0; c < 2; ++c) {
            bf16x8 bb[4];
#pragma unroll
            for (int nt = 0; nt < 4; ++nt)
                bb[nt] = __builtin_bit_cast(bf16x8, B4[((kk * 2 + c) * 4 + nt) * 64 + lane]);
            bf16x8 a[2];
#pragma unroll
            for (int t = 0; t < 2; ++t) {
                int px = ibase[t] + koff;
                int u16 = px * 8 + ((c * 4 + seg) ^ (px & 7));
                a[t] = __builtin_bit_cast(bf16x8, *reinterpret_cast<const uint4*>(&xs[u16 * 8]));
            }
#pragma unroll
            for (int t = 0; t < 2; ++t)
#pragma unroll
                for (int nt = 0; nt < 4; ++nt)
                    acc[t][nt] = __builtin_amdgcn_mfma_f32_16x16x32_bf16(a[t], bb[nt], acc[t][nt], 0, 0, 0);
        }
    }

#pragma unroll
    for (int nt = 0; nt < 4; ++nt) {
        int c = nt * 16 + row;
        float bc = b[c];
#pragma unroll
        for (int t = 0; t < 2; ++t)
#pragma unroll
            for (int r = 0; r < 4; ++r) {
                int p = (tbase + t) * 16 + seg * 4 + r;
                if (p < 49)
                    y3[(size_t)(n0 + img) * 3136 + p * 64 + c] = f2bf(fmaxf(acc[t][nt][r] + bc, 0.f));
            }
    }
}

// ---------------- FC v2: bf16 MFMA (unchanged) ----------------
__global__ __launch_bounds__(256) void fc_kernel(const unsigned short* __restrict__ A,
                                                 const unsigned short* __restrict__ Bt,
                                                 const float* __restrict__ bias,
                                                 float* __restrict__ C) {
    __shared__ float Cs[64][65];
    int tid = threadIdx.x;
    int lane = tid & 63;
    int wv = tid >> 6;
    int bm = blockIdx.x & 31;
    int bn = blockIdx.x >> 5;
    int row = lane & 15, seg = lane >> 4;

    const uint4* B4 = reinterpret_cast<const uint4*>(Bt);
    f32x4 acc[4][4];
#pragma unroll
    for (int mf = 0; mf < 4; ++mf)
#pragma unroll
        for (int nf = 0; nf < 4; ++nf) acc[mf][nf] = (f32x4){0.f, 0.f, 0.f, 0.f};

    const unsigned short* Abase = A + (size_t)(bm * 64 + row) * 3136 + seg * 8;

#pragma unroll 1
    for (int kk = wv; kk < 100; kk += 4) {
        bf16x8 a[4], bb[4];
#pragma unroll
        for (int mf = 0; mf < 4; ++mf)
            a[mf] = __builtin_bit_cast(bf16x8,
                *reinterpret_cast<const uint4*>(Abase + (size_t)mf * 16 * 3136 + kk * 32));
#pragma unroll
        for (int nf = 0; nf < 4; ++nf)
            bb[nf] = __builtin_bit_cast(bf16x8, B4[(kk * 32 + bn * 4 + nf) * 64 + lane]);
#pragma unroll
        for (int mf = 0; mf < 4; ++mf)
#pragma unroll
            for (int nf = 0; nf < 4; ++nf)
                acc[mf][nf] = __builtin_amdgcn_mfma_f32_16x16x32_bf16(a[mf], bb[nf], acc[mf][nf], 0, 0, 0);
    }

#pragma unroll 1
    for (int w = 0; w < 4; ++w) {
        if (wv == w) {
#pragma unroll
            for (int mf = 0; mf < 4; ++mf)
#pragma unroll
                for (int nf = 0; nf < 4; ++nf)
#pragma unroll
                    for (int r = 0; r < 4; ++r) {
                        int rr = mf * 16 + seg * 4 + r;
                        int cc = nf * 16 + row;
                        if (w == 0) Cs[rr][cc] = acc[mf][nf][r];
                        else        Cs[rr][cc] += acc[mf][nf][r];
                    }
        }
        __syncthreads();
    }

    int r = tid >> 2, cq = (tid & 3) * 16;
#pragma unroll
    for (int q = 0; q < 4; ++q) {
        int c0 = cq + q * 4;
        float4 v = *reinterpret_cast<float4*>(&Cs[r][c0]);
        float4 bv = *reinterpret_cast<const float4*>(&bias[bn * 64 + c0]);
        v.x = fmaxf(v.x + bv.x, 0.f);
        v.y = fmaxf(v.y + bv.y, 0.f);
        v.z = fmaxf(v.z + bv.z, 0.f);
        v.w = fmaxf(v.w + bv.w, 0.f);
        *reinterpret_cast<float4*>(&C[(size_t)(bm * 64 + r) * 512 + bn * 64 + c0]) = v;
    }
}

// ---------------- proj: packed float2 output (unchanged) ----------------
__global__ __launch_bounds__(256) void proj_kernel(const float* __restrict__ h,
                                                   const float* __restrict__ winr,
                                                   const float* __restrict__ wini,
                                                   float2* __restrict__ pj) {
    int idx = blockIdx.x * 256 + threadIdx.x;
    int u = idx & 127;
    int n0 = (idx >> 7) * 8;
    float ar[8] = {}, ai[8] = {};
    for (int k = 0; k < 512; ++k) {
        float wrv = winr[k * 128 + u], wiv = wini[k * 128 + u];
#pragma unroll
        for (int g = 0; g < 8; ++g) {
            float hv = h[(size_t)(n0 + g) * 512 + k];
            ar[g] = fmaf(hv, wrv, ar[g]);
            ai[g] = fmaf(hv, wiv, ai[g]);
        }
    }
#pragma unroll
    for (int g = 0; g < 8; ++g)
        pj[(size_t)(n0 + g) * 128 + u] = make_float2(ar[g], ai[g]);
}

// ---------------- RNN scan v7: v5 + LDS-only barriers (loads/stores fly across) ----------------
__global__ __launch_bounds__(256, 1) void scan_kernel(const float* __restrict__ done,
                                                      const float* __restrict__ sr0,
                                                      const float* __restrict__ si0,
                                                      const unsigned short* __restrict__ wsc,
                                                      const float2* __restrict__ pj,
                                                      float2* __restrict__ hs) {
    __shared__ __align__(16) unsigned short stR[2048], stI[2048];
    __shared__ __align__(16) float npart[16][4];
    __shared__ float done_l[2048];
    int tid = threadIdx.x;
    int lane = tid & 63, wv = tid >> 6;          // 4 waves
    int row = lane & 15, seg = lane >> 4;
    int u0 = wv * 32 + row;
    int u1 = u0 + 16;

    // done -> LDS (once)
    for (int e = tid; e < 2048; e += 256) done_l[e] = done[e];

    // weights: tiles 2wv, 2wv+1, both comps, 4 k-slices — 64 VGPRs, forced resident
    const uint4* W4 = reinterpret_cast<const uint4*>(wsc);
    bf16x8 WR0[4], WI0[4], WR1[4], WI1[4];
#pragma unroll
    for (int ks = 0; ks < 4; ++ks) {
        WR0[ks] = __builtin_bit_cast(bf16x8, W4[((0 * 8 + 2 * wv) * 4 + ks) * 64 + lane]);
        WR1[ks] = __builtin_bit_cast(bf16x8, W4[((0 * 8 + 2 * wv + 1) * 4 + ks) * 64 + lane]);
        WI0[ks] = __builtin_bit_cast(bf16x8, W4[((1 * 8 + 2 * wv) * 4 + ks) * 64 + lane]);
        WI1[ks] = __builtin_bit_cast(bf16x8, W4[((1 * 8 + 2 * wv + 1) * 4 + ks) * 64 + lane]);
    }
    asm volatile("" : "+v"(WR0[0]), "+v"(WR0[1]), "+v"(WR0[2]), "+v"(WR0[3]));
    asm volatile("" : "+v"(WR1[0]), "+v"(WR1[1]), "+v"(WR1[2]), "+v"(WR1[3]));
    asm volatile("" : "+v"(WI0[0]), "+v"(WI0[1]), "+v"(WI0[2]), "+v"(WI0[3]));
    asm volatile("" : "+v"(WI1[0]), "+v"(WI1[1]), "+v"(WI1[2]), "+v"(WI1[3]));

    // state init with done[0] blend
    for (int e = tid; e < 2048; e += 256) {
        int uu = e & 127, b = e >> 7;
        float d = done[b];
        float sr = sr0[b * 128 + uu], si = si0[b * 128 + uu];
        float bsr = (1.f - d) * sr + d;
        float bsi = (1.f - d) * si;
        int sw = ((uu >> 3) ^ b);
        stR[b * 128 + sw * 8 + (uu & 7)] = f2bf(bsr);
        stI[b * 128 + sw * 8 + (uu & 7)] = f2bf(bsi);
    }
    LDS_BARRIER();

    // prefetch t=0 proj
    float2 pjc0[4], pjc1[4];
#pragma unroll
    for (int r = 0; r < 4; ++r) {
        int b = seg * 4 + r;
        pjc0[r] = pj[(size_t)b * 128 + u0];
        pjc1[r] = pj[(size_t)b * 128 + u1];
    }

    for (int t = 0; t < T_STEPS; ++t) {
        // prefetch proj t+1 (stays in flight across the LDS-only barriers)
        float2 pjn0[4], pjn1[4];
        float dn[4];
        int tn = (t + 1 < T_STEPS) ? t + 1 : 127;
#pragma unroll
        for (int r = 0; r < 4; ++r) {
            int b = seg * 4 + r;
            pjn0[r] = pj[(size_t)(tn * 16 + b) * 128 + u0];
            pjn1[r] = pj[(size_t)(tn * 16 + b) * 128 + u1];
            dn[r] = (t + 1 < T_STEPS) ? done_l[(t + 1) * 16 + b] : 0.f;
        }

        // A-frags from state LDS (b = row); shared by both n-tiles
        bf16x8 aR[4], aI[4], aIn[4];
#pragma unroll
        for (int ks = 0; ks < 4; ++ks) {
            int unit = (ks * 4 + seg) ^ row;
            aR[ks] = __builtin_bit_cast(bf16x8,
                *reinterpret_cast<const uint4*>(&stR[row * 128 + unit * 8]));
            uint4 vi = *reinterpret_cast<const uint4*>(&stI[row * 128 + unit * 8]);
            aI[ks] = __builtin_bit_cast(bf16x8, vi);
            uint4 vn = {vi.x ^ 0x80008000u, vi.y ^ 0x80008000u,
                        vi.z ^ 0x80008000u, vi.w ^ 0x80008000u};
            aIn[ks] = __builtin_bit_cast(bf16x8, vn);
        }

        f32x4 accR0 = {0.f, 0.f, 0.f, 0.f}, accI0 = {0.f, 0.f, 0.f, 0.f};
        f32x4 accR1 = {0.f, 0.f, 0.f, 0.f}, accI1 = {0.f, 0.f, 0.f, 0.f};
#pragma unroll
        for (int ks = 0; ks < 4; ++ks) {
            accR0 = __builtin_amdgcn_mfma_f32_16x16x32_bf16(aR[ks], WR0[ks], accR0, 0, 0, 0);
            accR0 = __builtin_amdgcn_mfma_f32_16x16x32_bf16(aIn[ks], WI0[ks], accR0, 0, 0, 0);
            accI0 = __builtin_amdgcn_mfma_f32_16x16x32_bf16(aR[ks], WI0[ks], accI0, 0, 0, 0);
            accI0 = __builtin_amdgcn_mfma_f32_16x16x32_bf16(aI[ks], WR0[ks], accI0, 0, 0, 0);
            accR1 = __builtin_amdgcn_mfma_f32_16x16x32_bf16(aR[ks], WR1[ks], accR1, 0, 0, 0);
            accR1 = __builtin_amdgcn_mfma_f32_16x16x32_bf16(aIn[ks], WI1[ks], accR1, 0, 0, 0);
            accI1 = __builtin_amdgcn_mfma_f32_16x16x32_bf16(aR[ks], WI1[ks], accI1, 0, 0, 0);
            accI1 = __builtin_amdgcn_mfma_f32_16x16x32_bf16(aI[ks], WR1[ks], accI1, 0, 0, 0);
        }

        float prer0[4], prei0[4], prer1[4], prei1[4], sq[4];
#pragma unroll
        for (int r = 0; r < 4; ++r) {
            prer0[r] = accR0[r] + pjc0[r].x;
            prei0[r] = accI0[r] + pjc0[r].y;
            prer1[r] = accR1[r] + pjc1[r].x;
            prei1[r] = accI1[r] + pjc1[r].y;
            float s0 = fmaf(prer0[r], prer0[r], prei0[r] * prei0[r]);
            float s1 = fmaf(prer1[r], prer1[r], prei1[r] * prei1[r]);
            sq[r] = s0 + s1;
        }
#pragma unroll
        for (int off = 1; off <= 8; off <<= 1) {
#pragma unroll
            for (int r = 0; r < 4; ++r) sq[r] += __shfl_xor(sq[r], off);
        }
        if (row == 0) {
#pragma unroll
            for (int r = 0; r < 4; ++r) npart[seg * 4 + r][wv] = sq[r];
        }
        LDS_BARRIER();                        // bar 1 (LDS-only drain)

#pragma unroll
        for (int r = 0; r < 4; ++r) {
            int b = seg * 4 + r;
            float4 np = *reinterpret_cast<const float4*>(&npart[b][0]);
            float nm = (np.x + np.y) + (np.z + np.w);
            float scale = NORM_SCALE * rsqrtf(nm);
            float nr0 = prer0[r] * scale, ni0 = prei0[r] * scale;
            float nr1 = prer1[r] * scale, ni1 = prei1[r] * scale;
            hs[(size_t)(t * 16 + b) * 128 + u0] = make_float2(nr0, ni0);
            hs[(size_t)(t * 16 + b) * 128 + u1] = make_float2(nr1, ni1);
            float rr = 1.f - dn[r];
            int sw0 = ((u0 >> 3) ^ b);
            int sw1 = ((u1 >> 3) ^ b);
            stR[b * 128 + sw0 * 8 + (u0 & 7)] = f2bf(rr * nr0 + dn[r]);
            stI[b * 128 + sw0 * 8 + (u0 & 7)] = f2bf(rr * ni0);
            stR[b * 128 + sw1 * 8 + (u1 & 7)] = f2bf(rr * nr1 + dn[r]);
            stI[b * 128 + sw1 * 8 + (u1 & 7)] = f2bf(rr * ni1);
        }
        LDS_BARRIER();                        // bar 2 (LDS-only drain)
#pragma unroll
        for (int r = 0; r < 4; ++r) { pjc0[r] = pjn0[r]; pjc1[r] = pjn1[r]; }
    }
}

// ---------------- heads: packed float2 hs input (unchanged) ----------------
__global__ void heads_kernel(const float2* __restrict__ hs,
                             const float* __restrict__ aw, const float* __restrict__ ab,
                             const float* __restrict__ cw, const float* __restrict__ cb,
                             float* __restrict__ out) {
    int idx = blockIdx.x * 256 + threadIdx.x;
    if (idx >= N_FRAMES * 7) return;
    int j = idx % 7;
    int n = idx / 7;
    const float2* hp = hs + (size_t)n * 128;
    float acc;
    if (j < 6) {
        acc = ab[j];
        for (int k = 0; k < 128; ++k) {
            float2 v = hp[k];
            acc = fmaf(v.x, aw[k * 6 + j], acc);
            acc = fmaf(v.y, aw[(128 + k) * 6 + j], acc);
        }
    } else {
        acc = cb[0];
        for (int k = 0; k < 128; ++k) {
            float2 v = hp[k];
            acc = fmaf(v.x, cw[k], acc);
            acc = fmaf(v.y, cw[128 + k], acc);
        }
    }
    out[idx] = acc;
}

// ---------------- launch ----------------
extern "C" void kernel_launch(void* const* d_in, const int* in_sizes, int n_in,
                              void* d_out, int out_size, void* d_ws, size_t ws_size,
                              hipStream_t stream) {
    const float* x        = (const float*)d_in[0];
    const float* done     = (const float*)d_in[1];
    const float* sr0      = (const float*)d_in[2];
    const float* si0      = (const float*)d_in[3];
    const float* conv1_w  = (const float*)d_in[4];
    const float* conv1_b  = (const float*)d_in[5];
    const float* conv2_w  = (const float*)d_in[6];
    const float* conv2_b  = (const float*)d_in[7];
    const float* conv3_w  = (const float*)d_in[8];
    const float* conv3_b  = (const float*)d_in[9];
    const float* fc_w     = (const float*)d_in[10];
    const float* fc_b     = (const float*)d_in[11];
    const float* win_r    = (const float*)d_in[12];
    const float* win_i    = (const float*)d_in[13];
    const float* wrec_r   = (const float*)d_in[14];
    const float* wrec_i   = (const float*)d_in[15];
    const float* actor_w  = (const float*)d_in[16];
    const float* actor_b  = (const float*)d_in[17];
    const float* critic_w = (const float*)d_in[18];
    const float* critic_b = (const float*)d_in[19];

    float* ws = (float*)d_ws;
    unsigned short* w1mf = (unsigned short*)(ws + OFF_W1P);
    unsigned short* w2mf = (unsigned short*)(ws + OFF_W2P);
    unsigned short* w3mf = (unsigned short*)(ws + OFF_W3P);
    unsigned short* fcb = (unsigned short*)(ws + OFF_FCWP);
    unsigned short* wsc = (unsigned short*)(ws + OFF_WSC);
    float2* hs  = (float2*)(ws + OFF_HSR);
    float2* pj  = (float2*)(ws + OFF_PROJR);
    float* h    = ws + OFF_H;
    unsigned short* y2b = (unsigned short*)(ws + OFF_Y2);
    unsigned short* y1b = (unsigned short*)(ws + OFF_Y1);
    unsigned short* y3b = (unsigned short*)(ws + OFF_Y3);
    float* outp = (float*)d_out;

    hipLaunchKernelGGL(permute_w1mf, dim3(32), dim3(256), 0, stream, conv1_w, w1mf);
    hipLaunchKernelGGL(permute_w2mf, dim3(128), dim3(256), 0, stream, conv2_w, w2mf);
    hipLaunchKernelGGL(permute_w3mf, dim3(144), dim3(256), 0, stream, conv3_w, w3mf);
    hipLaunchKernelGGL(permute_fcwmf, dim3(6400), dim3(256), 0, stream, fc_w, fcb);
    hipLaunchKernelGGL(permute_wscan, dim3(128), dim3(256), 0, stream, wrec_r, wrec_i, wsc);

    hipLaunchKernelGGL(conv1_kernel, dim3(4096), dim3(256), 0, stream, x, w1mf, conv1_b, y1b);
    hipLaunchKernelGGL(conv2_kernel, dim3(1024), dim3(256), 0, stream, y1b, w2mf, conv2_b, y2b);
    hipLaunchKernelGGL(conv3_kernel, dim3(1024), dim3(256), 0, stream, y2b, w3mf, conv3_b, y3b);
    hipLaunchKernelGGL(fc_kernel, dim3(256), dim3(256), 0, stream, y3b, fcb, fc_b, h);
    hipLaunchKernelGGL(proj_kernel, dim3(128), dim3(256), 0, stream, h, win_r, win_i, pj);
    hipLaunchKernelGGL(scan_kernel, dim3(1), dim3(256), 0, stream,
                       done, sr0, si0, wsc, pj, hs);
    hipLaunchKernelGGL(heads_kernel, dim3(56), dim3(256), 0, stream,
                       hs, actor_w, actor_b, critic_w, critic_b, outp);
}

// Round 17
// 383.864 us; speedup vs baseline: 1.2991x; 1.0464x over previous
//
#include <hip/hip_runtime.h>
#include <hip/hip_bf16.h>

// ---------------- problem constants ----------------
#define N_FRAMES 2048          // T*B
#define T_STEPS  128
#define BATCH    16
#define UNITS    128
#define NORM_SCALE 11.313708498984760390f  // sqrt(128)

typedef short bf16x8 __attribute__((ext_vector_type(8)));
typedef float f32x4 __attribute__((ext_vector_type(4)));

static __device__ inline unsigned short f2bf(float f) {
    __hip_bfloat16 h = __float2bfloat16(f);
    return __builtin_bit_cast(unsigned short, h);
}

// LDS-only barrier: drains lgkm (LDS) but leaves global loads/stores in flight.
#define LDS_BARRIER() do { asm volatile("s_waitcnt lgkmcnt(0)" ::: "memory"); \
                           __builtin_amdgcn_s_barrier(); } while (0)

// ---------------- workspace layout (float elements) ----------------
static const size_t OFF_W1P   = 0;            // 16KB ush: conv1 MFMA weights [ky][nt][lane][8]
static const size_t OFF_W2P   = 6144;         // 64KB ush: conv2 MFMA B-frags [16][4][64][8]
static const size_t OFF_W3P   = 38912;        // 72KB ush: conv3 MFMA B-frags [9][2][4][64][8]
static const size_t OFF_FCWP  = 75776;        // ush: fc MFMA B-frags [100][32][64][8]
static const size_t OFF_HSR   = 1681408;      // 262144
static const size_t OFF_HSI   = 1943552;      // 262144
static const size_t OFF_PROJR = 2205696;      // 262144
static const size_t OFF_PROJI = 2467840;      // 262144
static const size_t OFF_H     = 2729984;      // 1048576 : fc output [2048][512] f32
static const size_t OFF_Y2    = 3778560;      // ush: y2 bf16 [2048][9][9][64]
static const size_t OFF_WRTR  = OFF_Y2;       // 16384 f32: wrec_r transposed (after conv3 consumed y2)
static const size_t OFF_WRTI  = OFF_Y2 + 16384; // 16384 f32: wrec_i transposed
static const size_t OFF_Y1    = 14395392;     // ush: y1 bf16 [2048][20][20][32]
static const size_t OFF_Y3    = OFF_Y1;       // ush: y3 bf16 [2048][3136] (reuses y1 after conv2)

// ---------------- weight permutes ----------------
__global__ void permute_w1mf(const float* __restrict__ w, unsigned short* __restrict__ o) {
    int i = blockIdx.x * 256 + threadIdx.x;      // 8192
    if (i >= 8192) return;
    int j = i & 7; int lane = (i >> 3) & 63; int nt = (i >> 9) & 1; int ky = i >> 10;
    int t = (lane >> 4) * 8 + j;
    int oc = nt * 16 + (lane & 15);
    float v = 0.f;
    if (t < 24) {
        int kx = t / 3, ic = t % 3;
        v = w[((oc * 3 + ic) * 8 + ky) * 8 + kx] * (1.0f / 255.0f);
    }
    o[i] = f2bf(v);
}
__global__ void permute_w2mf(const float* __restrict__ w, unsigned short* __restrict__ o) {
    int i = blockIdx.x * 256 + threadIdx.x;      // 32768
    if (i >= 32768) return;
    int j = i & 7; int lane = (i >> 3) & 63; int nt = (i >> 9) & 3; int kk = i >> 11;
    int ic = (lane >> 4) * 8 + j;
    int oc = nt * 16 + (lane & 15);
    int ky = kk >> 2, kx = kk & 3;
    o[i] = f2bf(w[((oc * 32 + ic) * 4 + ky) * 4 + kx]);
}
__global__ void permute_w3mf(const float* __restrict__ w, unsigned short* __restrict__ o) {
    int i = blockIdx.x * 256 + threadIdx.x;      // 36864
    if (i >= 36864) return;
    int j = i & 7; int lane = (i >> 3) & 63; int nt = (i >> 9) & 3; int c = (i >> 11) & 1; int kk = i >> 12;
    int ic = c * 32 + (lane >> 4) * 8 + j;
    int oc = nt * 16 + (lane & 15);
    int ky = kk / 3, kx = kk % 3;
    o[i] = f2bf(w[((oc * 64 + ic) * 3 + ky) * 3 + kx]);
}
__global__ void permute_fcwmf(const float* __restrict__ w, unsigned short* __restrict__ o) {
    int i = blockIdx.x * 256 + threadIdx.x;      // 1638400
    if (i >= 1638400) return;
    int jj = i & 7; int lane = (i >> 3) & 63; int ntg = (i >> 9) & 31; int kk = i >> 14;
    int k = kk * 32 + (lane >> 4) * 8 + jj;
    int n = ntg * 16 + (lane & 15);
    float v = 0.f;
    if (k < 3136) {
        int p = k >> 6, c = k & 63;
        v = w[(size_t)(c * 49 + p) * 512 + n];
    }
    o[i] = f2bf(v);
}
__global__ void permute_wrt(const float* __restrict__ wr, const float* __restrict__ wi,
                            float* __restrict__ otr, float* __restrict__ oti) {
    int i = blockIdx.x * 256 + threadIdx.x;      // 16384
    if (i >= 16384) return;
    int k = i & 127, u = i >> 7;
    otr[i] = wr[k * 128 + u];
    oti[i] = wi[k * 128 + u];
}

// ---------------- conv1 v6: MFMA implicit GEMM, bf16 output ----------------
__global__ __launch_bounds__(256) void conv1_kernel(const float* __restrict__ x,
                                                    const unsigned short* __restrict__ wmf,
                                                    const float* __restrict__ b,
                                                    unsigned short* __restrict__ y) {
    __shared__ unsigned short xs[11096];
    int tid = threadIdx.x;
    int blk = blockIdx.x;
    int n = blk >> 1, hb = blk & 1;

    const float4* xb4 = reinterpret_cast<const float4*>(x + (size_t)n * 21168 + hb * 40 * 252);
#pragma unroll
    for (int it = 0; it < 11; ++it) {
        int i = it * 256 + tid;
        if (i < 2772) {
            float4 v = xb4[i];
            ushort4 h;
            h.x = f2bf(v.x); h.y = f2bf(v.y); h.z = f2bf(v.z); h.w = f2bf(v.w);
            *reinterpret_cast<ushort4*>(&xs[i * 4]) = h;
        }
    }
    if (tid < 8) xs[11088 + tid] = 0;
    __syncthreads();

    int lane = tid & 63;
    int wv = tid >> 6;
    int row = lane & 15;
    int seg = lane >> 4;
    const uint4* wm = reinterpret_cast<const uint4*>(wmf);
    float b0 = b[row];
    float b1 = b[16 + row];
    int pbase = n * 400 + hb * 200;

    for (int tile = wv; tile < 13; tile += 4) {
        int p = tile * 16 + row; if (p > 199) p = 199;
        int eb = (p / 20) * 1008 + (p % 20) * 12 + seg * 8;
        f32x4 acc0 = {0.f, 0.f, 0.f, 0.f};
        f32x4 acc1 = {0.f, 0.f, 0.f, 0.f};
#pragma unroll
        for (int ky = 0; ky < 8; ++ky) {
            int ea = eb + ky * 252;
            ushort4 lo = *reinterpret_cast<const ushort4*>(&xs[ea]);
            ushort4 hi = *reinterpret_cast<const ushort4*>(&xs[ea + 4]);
            bf16x8 a = {(short)lo.x, (short)lo.y, (short)lo.z, (short)lo.w,
                        (short)hi.x, (short)hi.y, (short)hi.z, (short)hi.w};
            bf16x8 w0 = __builtin_bit_cast(bf16x8, wm[(ky * 2 + 0) * 64 + lane]);
            bf16x8 w1 = __builtin_bit_cast(bf16x8, wm[(ky * 2 + 1) * 64 + lane]);
            acc0 = __builtin_amdgcn_mfma_f32_16x16x32_bf16(a, w0, acc0, 0, 0, 0);
            acc1 = __builtin_amdgcn_mfma_f32_16x16x32_bf16(a, w1, acc1, 0, 0, 0);
        }
#pragma unroll
        for (int r = 0; r < 4; ++r) {
            int pl = tile * 16 + seg * 4 + r;
            if (pl < 200) {
                unsigned short* yp = y + ((size_t)(pbase + pl)) * 32 + row;
                yp[0]  = f2bf(fmaxf(acc0[r] + b0, 0.f));
                yp[16] = f2bf(fmaxf(acc1[r] + b1, 0.f));
            }
        }
    }
}

// ---------------- conv2 v5: MFMA implicit GEMM, bf16 output ----------------
__global__ __launch_bounds__(256) void conv2_kernel(const unsigned short* __restrict__ y1b,
                                                    const unsigned short* __restrict__ wt,
                                                    const float* __restrict__ b,
                                                    unsigned short* __restrict__ y2) {
    __shared__ unsigned short xs[2 * 12800];
    int tid = threadIdx.x;
    int n0 = blockIdx.x * 2;
    const uint4* xg = reinterpret_cast<const uint4*>(y1b + (size_t)n0 * 12800);
    uint4* xs4 = reinterpret_cast<uint4*>(xs);
#pragma unroll
    for (int q = 0; q < 13; ++q) {
        int i = q * 256 + tid;
        if (i < 3200) {
            uint4 v = xg[i];
            int swz = (i & ~3) | ((i & 3) ^ ((i >> 3) & 3));
            xs4[swz] = v;
        }
    }
    __syncthreads();

    int lane = tid & 63;
    int wv = tid >> 6;
    int img = wv >> 1;
    int tbase = (wv & 1) * 3;
    int row = lane & 15, seg = lane >> 4;
    int imgb = img * 1600;

    int ibase[3];
#pragma unroll
    for (int t = 0; t < 3; ++t) {
        int p = (tbase + t) * 16 + row; if (p > 80) p = 80;
        ibase[t] = (p / 9) * 40 + (p % 9) * 2;
    }
    const uint4* B4 = reinterpret_cast<const uint4*>(wt);
    f32x4 acc[3][4];
#pragma unroll
    for (int t = 0; t < 3; ++t)
#pragma unroll
        for (int nt = 0; nt < 4; ++nt) acc[t][nt] = (f32x4){0.f, 0.f, 0.f, 0.f};

#pragma unroll 1
    for (int kk = 0; kk < 16; ++kk) {
        int ky = kk >> 2, kx = kk & 3;
        int koff = ky * 20 + kx;
        bf16x8 bb[4];
#pragma unroll
        for (int nt = 0; nt < 4; ++nt)
            bb[nt] = __builtin_bit_cast(bf16x8, B4[(kk * 4 + nt) * 64 + lane]);
        bf16x8 a[3];
#pragma unroll
        for (int t = 0; t < 3; ++t) {
            int ipx = ibase[t] + koff;
            int a16 = imgb + ipx * 4 + (seg ^ ((ipx >> 1) & 3));
            a[t] = __builtin_bit_cast(bf16x8, *reinterpret_cast<const uint4*>(&xs[a16 * 8]));
        }
#pragma unroll
        for (int t = 0; t < 3; ++t)
#pragma unroll
            for (int nt = 0; nt < 4; ++nt)
                acc[t][nt] = __builtin_amdgcn_mfma_f32_16x16x32_bf16(a[t], bb[nt], acc[t][nt], 0, 0, 0);
    }

#pragma unroll
    for (int nt = 0; nt < 4; ++nt) {
        int c = nt * 16 + row;
        float bc = b[c];
#pragma unroll
        for (int t = 0; t < 3; ++t)
#pragma unroll
            for (int r = 0; r < 4; ++r) {
                int p = (tbase + t) * 16 + seg * 4 + r;
                if (p < 81)
                    y2[((size_t)(n0 + img) * 81 + p) * 64 + c] = f2bf(fmaxf(acc[t][nt][r] + bc, 0.f));
            }
    }
}

// ---------------- conv3 v5: MFMA implicit GEMM, bf16 output ----------------
__global__ __launch_bounds__(256) void conv3_kernel(const unsigned short* __restrict__ y2b,
                                                    const unsigned short* __restrict__ wt,
                                                    const float* __restrict__ b,
                                                    unsigned short* __restrict__ y3) {
    __shared__ unsigned short xs[2 * 5184];
    int tid = threadIdx.x;
    int n0 = blockIdx.x * 2;
    const uint4* xg = reinterpret_cast<const uint4*>(y2b + (size_t)n0 * 5184);
    uint4* xs4 = reinterpret_cast<uint4*>(xs);
#pragma unroll
    for (int q = 0; q < 6; ++q) {
        int i = q * 256 + tid;
        if (i < 1296) {
            uint4 v = xg[i];
            int px = i >> 3, qq = i & 7;
            xs4[px * 8 + (qq ^ (px & 7))] = v;
        }
    }
    __syncthreads();

    int lane = tid & 63;
    int wv = tid >> 6;
    int img = wv >> 1;
    int tbase = (wv & 1) * 2;
    int row = lane & 15, seg = lane >> 4;

    int ibase[2];
#pragma unroll
    for (int t = 0; t < 2; ++t) {
        int p = (tbase + t) * 16 + row; if (p > 48) p = 48;
        ibase[t] = img * 81 + (p / 7) * 9 + (p % 7);
    }
    const uint4* B4 = reinterpret_cast<const uint4*>(wt);
    f32x4 acc[2][4];
#pragma unroll
    for (int t = 0; t < 2; ++t)
#pragma unroll
        for (int nt = 0; nt < 4; ++nt) acc[t][nt] = (f32x4){0.f, 0.f, 0.f, 0.f};

#pragma unroll 1
    for (int kk = 0; kk < 9; ++kk) {
        int ky = kk / 3, kx = kk % 3;
        int koff = ky * 9 + kx;
#pragma unroll
        for (int c = 0; c < 2; ++c) {
            bf16x8 bb[4];
#pragma unroll
            for (int nt = 0; nt < 4; ++nt)
                bb[nt] = __builtin_bit_cast(bf16x8, B4[((kk * 2 + c) * 4 + nt) * 64 + lane]);
            bf16x8 a[2];
#pragma unroll
            for (int t = 0; t < 2; ++t) {
                int px = ibase[t] + koff;
                int u16 = px * 8 + ((c * 4 + seg) ^ (px & 7));
                a[t] = __builtin_bit_cast(bf16x8, *reinterpret_cast<const uint4*>(&xs[u16 * 8]));
            }
#pragma unroll
            for (int t = 0; t < 2; ++t)
#pragma unroll
                for (int nt = 0; nt < 4; ++nt)
                    acc[t][nt] = __builtin_amdgcn_mfma_f32_16x16x32_bf16(a[t], bb[nt], acc[t][nt], 0, 0, 0);
        }
    }

#pragma unroll
    for (int nt = 0; nt < 4; ++nt) {
        int c = nt * 16 + row;
        float bc = b[c];
#pragma unroll
        for (int t = 0; t < 2; ++t)
#pragma unroll
            for (int r = 0; r < 4; ++r) {
                int p = (tbase + t) * 16 + seg * 4 + r;
                if (p < 49)
                    y3[(size_t)(n0 + img) * 3136 + p * 64 + c] = f2bf(fmaxf(acc[t][nt][r] + bc, 0.f));
            }
    }
}

// ---------------- FC v2: bf16 MFMA ----------------
__global__ __launch_bounds__(256) void fc_kernel(const unsigned short* __restrict__ A,
                                                 const unsigned short* __restrict__ Bt,
                                                 const float* __restrict__ bias,
                                                 float* __restrict__ C) {
    __shared__ float Cs[64][65];
    int tid = threadIdx.x;
    int lane = tid & 63;
    int wv = tid >> 6;
    int bm = blockIdx.x & 31;
    int bn = blockIdx.x >> 5;
    int row = lane & 15, seg = lane >> 4;

    const uint4* B4 = reinterpret_cast<const uint4*>(Bt);
    f32x4 acc[4][4];
#pragma unroll
    for (int mf = 0; mf < 4; ++mf)
#pragma unroll
        for (int nf = 0; nf < 4; ++nf) acc[mf][nf] = (f32x4){0.f, 0.f, 0.f, 0.f};

    const unsigned short* Abase = A + (size_t)(bm * 64 + row) * 3136 + seg * 8;

#pragma unroll 1
    for (int kk = wv; kk < 100; kk += 4) {
        bf16x8 a[4], bb[4];
#pragma unroll
        for (int mf = 0; mf < 4; ++mf)
            a[mf] = __builtin_bit_cast(bf16x8,
                *reinterpret_cast<const uint4*>(Abase + (size_t)mf * 16 * 3136 + kk * 32));
#pragma unroll
        for (int nf = 0; nf < 4; ++nf)
            bb[nf] = __builtin_bit_cast(bf16x8, B4[(kk * 32 + bn * 4 + nf) * 64 + lane]);
#pragma unroll
        for (int mf = 0; mf < 4; ++mf)
#pragma unroll
            for (int nf = 0; nf < 4; ++nf)
                acc[mf][nf] = __builtin_amdgcn_mfma_f32_16x16x32_bf16(a[mf], bb[nf], acc[mf][nf], 0, 0, 0);
    }

#pragma unroll 1
    for (int w = 0; w < 4; ++w) {
        if (wv == w) {
#pragma unroll
            for (int mf = 0; mf < 4; ++mf)
#pragma unroll
                for (int nf = 0; nf < 4; ++nf)
#pragma unroll
                    for (int r = 0; r < 4; ++r) {
                        int rr = mf * 16 + seg * 4 + r;
                        int cc = nf * 16 + row;
                        if (w == 0) Cs[rr][cc] = acc[mf][nf][r];
                        else        Cs[rr][cc] += acc[mf][nf][r];
                    }
        }
        __syncthreads();
    }

    int r = tid >> 2, cq = (tid & 3) * 16;
#pragma unroll
    for (int q = 0; q < 4; ++q) {
        int c0 = cq + q * 4;
        float4 v = *reinterpret_cast<float4*>(&Cs[r][c0]);
        float4 bv = *reinterpret_cast<const float4*>(&bias[bn * 64 + c0]);
        v.x = fmaxf(v.x + bv.x, 0.f);
        v.y = fmaxf(v.y + bv.y, 0.f);
        v.z = fmaxf(v.z + bv.z, 0.f);
        v.w = fmaxf(v.w + bv.w, 0.f);
        *reinterpret_cast<float4*>(&C[(size_t)(bm * 64 + r) * 512 + bn * 64 + c0]) = v;
    }
}

// ---------------- proj ----------------
__global__ __launch_bounds__(256) void proj_kernel(const float* __restrict__ h,
                                                   const float* __restrict__ winr,
                                                   const float* __restrict__ wini,
                                                   float* __restrict__ pr,
                                                   float* __restrict__ pi) {
    int idx = blockIdx.x * 256 + threadIdx.x;
    int u = idx & 127;
    int n0 = (idx >> 7) * 8;
    float ar[8] = {}, ai[8] = {};
    for (int k = 0; k < 512; ++k) {
        float wrv = winr[k * 128 + u], wiv = wini[k * 128 + u];
#pragma unroll
        for (int g = 0; g < 8; ++g) {
            float hv = h[(size_t)(n0 + g) * 512 + k];
            ar[g] = fmaf(hv, wrv, ar[g]);
            ai[g] = fmaf(hv, wiv, ai[g]);
        }
    }
#pragma unroll
    for (int g = 0; g < 8; ++g) {
        pr[(size_t)(n0 + g) * 128 + u] = ar[g];
        pi[(size_t)(n0 + g) * 128 + u] = ai[g];
    }
}

// ---------------- RNN scan v2 + LDS-only barriers ----------------
__global__ __launch_bounds__(512) void scan_kernel(const float* __restrict__ done,
                                                   const float* __restrict__ sr0,
                                                   const float* __restrict__ si0,
                                                   const float* __restrict__ wrtR,
                                                   const float* __restrict__ wrtI,
                                                   const float* __restrict__ pr,
                                                   const float* __restrict__ pi,
                                                   float* __restrict__ hsr,
                                                   float* __restrict__ hsi) {
    int b = blockIdx.x;
    int tid = threadIdx.x;
    int u = tid & 127;
    int s = tid >> 7;
    int w = tid >> 6;

    const float4* wr4 = reinterpret_cast<const float4*>(wrtR + u * 128 + s * 32);
    const float4* wi4 = reinterpret_cast<const float4*>(wrtI + u * 128 + s * 32);
    float4 WR[8], WI[8];
#pragma unroll
    for (int q = 0; q < 8; ++q) { WR[q] = wr4[q]; WI[q] = wi4[q]; }

    __shared__ __align__(16) float stR[128], stI[128];
    __shared__ float parR[4][128], parI[4][128];
    __shared__ float redw[8];

    if (s == 0) { stR[u] = sr0[b * 128 + u]; stI[u] = si0[b * 128 + u]; }
    float cr = 0.f, ci = 0.f;
#pragma unroll
    for (int q = 0; q < 8; ++q) {
        cr += WR[q].x + WR[q].y + WR[q].z + WR[q].w;
        ci += WI[q].x + WI[q].y + WI[q].z + WI[q].w;
    }
    parR[s][u] = cr; parI[s][u] = ci;
    LDS_BARRIER();
    float SWr = parR[0][u] + parR[1][u] + parR[2][u] + parR[3][u];
    float SWi = parI[0][u] + parI[1][u] + parI[2][u] + parI[3][u];
    LDS_BARRIER();

    for (int t = 0; t < T_STEPS; ++t) {
        int np = (t * BATCH + b) * 128 + u;
        float prr = pr[np];
        float pri = pi[np];
        float d = done[t * BATCH + b];
        float r = 1.f - d;

        const float4* sR4 = reinterpret_cast<const float4*>(&stR[s * 32]);
        const float4* sI4 = reinterpret_cast<const float4*>(&stI[s * 32]);
        float ar0 = 0.f, ar1 = 0.f, ai0 = 0.f, ai1 = 0.f;
#pragma unroll
        for (int q = 0; q < 8; ++q) {
            float4 sr = sR4[q], si = sI4[q];
            float4 wrv = WR[q], wiv = WI[q];
            if (q & 1) {
                ar1 = fmaf(sr.x, wrv.x, ar1); ar1 = fmaf(-si.x, wiv.x, ar1);
                ai1 = fmaf(sr.x, wiv.x, ai1); ai1 = fmaf(si.x, wrv.x, ai1);
                ar1 = fmaf(sr.y, wrv.y, ar1); ar1 = fmaf(-si.y, wiv.y, ar1);
                ai1 = fmaf(sr.y, wiv.y, ai1); ai1 = fmaf(si.y, wrv.y, ai1);
                ar1 = fmaf(sr.z, wrv.z, ar1); ar1 = fmaf(-si.z, wiv.z, ar1);
                ai1 = fmaf(sr.z, wiv.z, ai1); ai1 = fmaf(si.z, wrv.z, ai1);
                ar1 = fmaf(sr.w, wrv.w, ar1); ar1 = fmaf(-si.w, wiv.w, ar1);
                ai1 = fmaf(sr.w, wiv.w, ai1); ai1 = fmaf(si.w, wrv.w, ai1);
            } else {
                ar0 = fmaf(sr.x, wrv.x, ar0); ar0 = fmaf(-si.x, wiv.x, ar0);
                ai0 = fmaf(sr.x, wiv.x, ai0); ai0 = fmaf(si.x, wrv.x, ai0);
                ar0 = fmaf(sr.y, wrv.y, ar0); ar0 = fmaf(-si.y, wiv.y, ar0);
                ai0 = fmaf(sr.y, wiv.y, ai0); ai0 = fmaf(si.y, wrv.y, ai0);
                ar0 = fmaf(sr.z, wrv.z, ar0); ar0 = fmaf(-si.z, wiv.z, ar0);
                ai0 = fmaf(sr.z, wiv.z, ai0); ai0 = fmaf(si.z, wrv.z, ai0);
                ar0 = fmaf(sr.w, wrv.w, ar0); ar0 = fmaf(-si.w, wiv.w, ar0);
                ai0 = fmaf(sr.w, wiv.w, ai0); ai0 = fmaf(si.w, wrv.w, ai0);
            }
        }
        parR[s][u] = ar0 + ar1;
        parI[s][u] = ai0 + ai1;
        LDS_BARRIER();                                   // bar 1 (LDS-only)

        float tr_ = (parR[0][u] + parR[1][u]) + (parR[2][u] + parR[3][u]);
        float ti_ = (parI[0][u] + parI[1][u]) + (parI[2][u] + parI[3][u]);
        float pre_r = fmaf(r, tr_, fmaf(d, SWr, prr));
        float pre_i = fmaf(r, ti_, fmaf(d, SWi, pri));
        float sq = fmaf(pre_r, pre_r, pre_i * pre_i);
#pragma unroll
        for (int off = 32; off; off >>= 1) sq += __shfl_xor(sq, off);
        if ((tid & 63) == 0) redw[w] = sq;
        LDS_BARRIER();                                   // bar 2 (LDS-only)

        float norm = redw[s * 2] + redw[s * 2 + 1];
        float scale = NORM_SCALE * rsqrtf(norm);
        float nr = pre_r * scale, ni = pre_i * scale;
        if (s == 0) {
            stR[u] = nr; stI[u] = ni;
            hsr[np] = nr; hsi[np] = ni;
        }
        LDS_BARRIER();                                   // bar 3 (LDS-only)
    }
}

// ---------------- heads ----------------
__global__ void heads_kernel(const float* __restrict__ hsr, const float* __restrict__ hsi,
                             const float* __restrict__ aw, const float* __restrict__ ab,
                             const float* __restrict__ cw, const float* __restrict__ cb,
                             float* __restrict__ out) {
    int idx = blockIdx.x * 256 + threadIdx.x;
    if (idx >= N_FRAMES * 7) return;
    int j = idx % 7;
    int n = idx / 7;
    float acc;
    if (j < 6) {
        acc = ab[j];
        for (int k = 0; k < 128; ++k) acc = fmaf(hsr[n * 128 + k], aw[k * 6 + j], acc);
        for (int k = 0; k < 128; ++k) acc = fmaf(hsi[n * 128 + k], aw[(128 + k) * 6 + j], acc);
    } else {
        acc = cb[0];
        for (int k = 0; k < 128; ++k) acc = fmaf(hsr[n * 128 + k], cw[k], acc);
        for (int k = 0; k < 128; ++k) acc = fmaf(hsi[n * 128 + k], cw[128 + k], acc);
    }
    out[idx] = acc;
}

// ---------------- launch ----------------
extern "C" void kernel_launch(void* const* d_in, const int* in_sizes, int n_in,
                              void* d_out, int out_size, void* d_ws, size_t ws_size,
                              hipStream_t stream) {
    const float* x        = (const float*)d_in[0];
    const float* done     = (const float*)d_in[1];
    const float* sr0      = (const float*)d_in[2];
    const float* si0      = (const float*)d_in[3];
    const float* conv1_w  = (const float*)d_in[4];
    const float* conv1_b  = (const float*)d_in[5];
    const float* conv2_w  = (const float*)d_in[6];
    const float* conv2_b  = (const float*)d_in[7];
    const float* conv3_w  = (const float*)d_in[8];
    const float* conv3_b  = (const float*)d_in[9];
    const float* fc_w     = (const float*)d_in[10];
    const float* fc_b     = (const float*)d_in[11];
    const float* win_r    = (const float*)d_in[12];
    const float* win_i    = (const float*)d_in[13];
    const float* wrec_r   = (const float*)d_in[14];
    const float* wrec_i   = (const float*)d_in[15];
    const float* actor_w  = (const float*)d_in[16];
    const float* actor_b  = (const float*)d_in[17];
    const float* critic_w = (const float*)d_in[18];
    const float* critic_b = (const float*)d_in[19];

    float* ws = (float*)d_ws;
    unsigned short* w1mf = (unsigned short*)(ws + OFF_W1P);
    unsigned short* w2mf = (unsigned short*)(ws + OFF_W2P);
    unsigned short* w3mf = (unsigned short*)(ws + OFF_W3P);
    unsigned short* fcb = (unsigned short*)(ws + OFF_FCWP);
    float* hsr  = ws + OFF_HSR;
    float* hsi  = ws + OFF_HSI;
    float* prj  = ws + OFF_PROJR;
    float* pij  = ws + OFF_PROJI;
    float* h    = ws + OFF_H;
    unsigned short* y2b = (unsigned short*)(ws + OFF_Y2);
    float* wrtR = ws + OFF_WRTR;
    float* wrtI = ws + OFF_WRTI;
    unsigned short* y1b = (unsigned short*)(ws + OFF_Y1);
    unsigned short* y3b = (unsigned short*)(ws + OFF_Y3);
    float* outp = (float*)d_out;

    hipLaunchKernelGGL(permute_w1mf, dim3(32), dim3(256), 0, stream, conv1_w, w1mf);
    hipLaunchKernelGGL(permute_w2mf, dim3(128), dim3(256), 0, stream, conv2_w, w2mf);
    hipLaunchKernelGGL(permute_w3mf, dim3(144), dim3(256), 0, stream, conv3_w, w3mf);
    hipLaunchKernelGGL(permute_fcwmf, dim3(6400), dim3(256), 0, stream, fc_w, fcb);

    hipLaunchKernelGGL(conv1_kernel, dim3(4096), dim3(256), 0, stream, x, w1mf, conv1_b, y1b);
    hipLaunchKernelGGL(conv2_kernel, dim3(1024), dim3(256), 0, stream, y1b, w2mf, conv2_b, y2b);
    hipLaunchKernelGGL(conv3_kernel, dim3(1024), dim3(256), 0, stream, y2b, w3mf, conv3_b, y3b);
    // y2 consumed; its space now holds the transposed recurrent weights
    hipLaunchKernelGGL(permute_wrt, dim3(64), dim3(256), 0, stream, wrec_r, wrec_i, wrtR, wrtI);
    hipLaunchKernelGGL(fc_kernel, dim3(256), dim3(256), 0, stream, y3b, fcb, fc_b, h);
    hipLaunchKernelGGL(proj_kernel, dim3(128), dim3(256), 0, stream, h, win_r, win_i, prj, pij);
    hipLaunchKernelGGL(scan_kernel, dim3(16), dim3(512), 0, stream,
                       done, sr0, si0, wrtR, wrtI, prj, pij, hsr, hsi);
    hipLaunchKernelGGL(heads_kernel, dim3(56), dim3(256), 0, stream,
                       hsr, hsi, actor_w, actor_b, critic_w, critic_b, outp);
}